// Round 9
// baseline (5172.376 us; speedup 1.0000x reference)
//
#include <hip/hip_runtime.h>
#include <hip/hip_bf16.h>

typedef __bf16 bf16x8 __attribute__((ext_vector_type(8)));
typedef float f32x4 __attribute__((ext_vector_type(4)));
typedef unsigned short u16;

#define GLD_LDS16(gp, lp) __builtin_amdgcn_global_load_lds( \
    (const __attribute__((address_space(1))) unsigned int*)(gp), \
    (__attribute__((address_space(3))) unsigned int*)(lp), 16, 0, 0)

__device__ __forceinline__ float tanh_fast(float x) {
  float e = __expf(2.0f * x);
  return 1.0f - __fdividef(2.0f, e + 1.0f);
}

__device__ __forceinline__ u16 bf16_rn(float x) {
  union { float f; unsigned u; } v; v.f = x;
  unsigned r = v.u + 0x7fffu + ((v.u >> 16) & 1u);
  return (u16)(r >> 16);
}

// ---------------------------------------------------------------------------
// Fused GEMM: C[M,N] = A[M,K] (bf16 row-major) x Bt[N,K]^T (bf16 row-major)
// R9 = R8 verbatim structure (2-barrier loop, 64-col LDS slabs, T2 both-sides
// XOR swizzle, XCD m-band swizzle, direct fragment epilogue) re-tiled for
// 3 blocks/CU (12 waves/CU, the m97 latency-hiding regime):
//   GEMM-A: 64x128, BK=128 -> 48KB LDS, grid 1024 (~3 blocks/CU)
//   GEMM-B: 32x64,  BK=256 -> 48KB LDS, grid 1024 (~3 blocks/CU)
// Rationale: corrected MFMA model (1 MFMA/5cy per CU) shows both GEMMs are
// MFMA-issue-bound with LDS at 40-80%; the 2.5x gap to the MFMA floor is
// exposed drain/epilogue serialization -> hide it with a 3rd resident block.
// MODE 0: out_bf = bf16(tanh(acc + bias + t*wt))
// MODE 1: v = 0.999*y + 0.001*z + h*(acc+bias); out32 = v; out_bf = v
// MODE 2: v = z + h*(acc+bias);                 out32 = v; out_bf = v
// ---------------------------------------------------------------------------
template <int BM, int BN, int BK, int K, int MODE, int NTL>
__global__ __launch_bounds__(256)
void gemm_fused(const u16* __restrict__ A, const u16* __restrict__ Bt,
                const float* __restrict__ bias, const float* __restrict__ wt,
                float tval,
                const float* __restrict__ y_in, const float* __restrict__ z_in,
                float* __restrict__ out32, u16* __restrict__ out_bf, int N) {
  constexpr int NS = BK / 64;                 // 64-col slabs
  constexpr int WTM = BM / 2, WTN = BN / 2;   // per-wave tile (2x2 wave grid)
  constexpr int FM = WTM / 16, FN = WTN / 16; // fragments per wave
  constexpr int ACH = BM * BK * 2 / 1024;     // 1KB staging chunks
  constexpr int BCH = BN * BK * 2 / 1024;
  constexpr int CPS_A = BM / 8;               // chunks per slab
  constexpr int CPS_B = BN / 8;
  constexpr int MT = 4096 / BM;               // m-tiles total
  constexpr int MPX = MT / 8;                 // m-tiles per XCD

  __shared__ u16 As[NS * BM * 64];  // [slab][row][64]
  __shared__ u16 Bs[NS * BN * 64];

  const int tid = threadIdx.x;
  const int wave = tid >> 6;
  const int lane = tid & 63;
  const int wm = wave >> 1, wn = wave & 1;
  const int l15 = lane & 15, kg = lane >> 4;

  const int wg = blockIdx.x;
  const int xcd = wg & 7;
  const int j = wg >> 3;
  const int bm0 = (xcd * MPX + j / NTL) * BM;
  const int bn0 = (j % NTL) * BN;

  f32x4 acc[FM][FN];
#pragma unroll
  for (int m = 0; m < FM; ++m)
#pragma unroll
    for (int n = 0; n < FN; ++n) acc[m][n] = (f32x4){0.f, 0.f, 0.f, 0.f};

  const int sr = lane >> 3;                     // row within 8-row (1KB) chunk
  const int scs = ((lane & 7) ^ sr) * 8;        // PRE-SWIZZLED src col (elements)
  const int rsw = (l15 & 7) << 3;               // read-side XOR (elements)

  const u16* Ag = A + (size_t)bm0 * K;
  const u16* Bg = Bt + (size_t)bn0 * K;

  for (int kt = 0; kt < K / BK; ++kt) {
    const u16* Ak = Ag + kt * BK;
    const u16* Bk = Bg + kt * BK;
#pragma unroll
    for (int i = 0; i < ACH / 4; ++i) {
      const int ch = wave + i * 4;
      const int kh = ch / CPS_A;   // slab index
      const int rg = ch % CPS_A;   // 8-row group
      GLD_LDS16(Ak + (size_t)(rg * 8 + sr) * K + kh * 64 + scs,
                (char*)As + ch * 1024);
    }
#pragma unroll
    for (int i = 0; i < BCH / 4; ++i) {
      const int ch = wave + i * 4;
      const int kh = ch / CPS_B;
      const int rg = ch % CPS_B;
      GLD_LDS16(Bk + (size_t)(rg * 8 + sr) * K + kh * 64 + scs,
                (char*)Bs + ch * 1024);
    }
    __syncthreads();
#pragma unroll
    for (int ks = 0; ks < 2 * NS; ++ks) {
      const int kh = ks >> 1;
      const int kc = ((ks & 1) * 32 + kg * 8) ^ rsw;  // swizzled read col
      bf16x8 af[FM], bfr[FN];
#pragma unroll
      for (int m = 0; m < FM; ++m)
        af[m] = *reinterpret_cast<const bf16x8*>(
            &As[(kh * BM + wm * WTM + m * 16 + l15) * 64 + kc]);
#pragma unroll
      for (int n = 0; n < FN; ++n)
        bfr[n] = *reinterpret_cast<const bf16x8*>(
            &Bs[(kh * BN + wn * WTN + n * 16 + l15) * 64 + kc]);
#pragma unroll
      for (int m = 0; m < FM; ++m)
#pragma unroll
        for (int n = 0; n < FN; ++n)
          acc[m][n] =
              __builtin_amdgcn_mfma_f32_16x16x32_bf16(af[m], bfr[n], acc[m][n], 0, 0, 0);
    }
    __syncthreads();
  }

  // Epilogue (R4 direct stores). C/D layout: col = lane&15, row = (lane>>4)*4 + reg.
#pragma unroll
  for (int n = 0; n < FN; ++n) {
    const int col = bn0 + wn * WTN + n * 16 + l15;
    const float bv = bias[col];
    const float wv = (MODE == 0) ? wt[col] : 0.f;
#pragma unroll
    for (int m = 0; m < FM; ++m) {
      const int row0 = bm0 + wm * WTM + m * 16 + kg * 4;
#pragma unroll
      for (int r = 0; r < 4; ++r) {
        const size_t idx = (size_t)(row0 + r) * N + col;
        const float a = acc[m][n][r];
        if (MODE == 0) {
          const float x = a + bv + tval * wv;
          out_bf[idx] = bf16_rn(tanh_fast(x));
        } else if (MODE == 1) {
          const float v = 0.999f * y_in[idx] + 0.001f * z_in[idx] +
                          0.015625f * (a + bv);
          out32[idx] = v;
          out_bf[idx] = bf16_rn(v);
        } else {
          const float v = z_in[idx] + 0.015625f * (a + bv);
          out32[idx] = v;
          out_bf[idx] = bf16_rn(v);
        }
      }
    }
  }
}

// in: [R, C] f32  ->  out: [C, R] bf16
__global__ void transpose_bf16(const float* __restrict__ in, u16* __restrict__ out,
                               int R, int C) {
  __shared__ float tile[32][33];
  const int bx = blockIdx.x * 32;
  const int by = blockIdx.y * 32;
  const int tx = threadIdx.x, ty = threadIdx.y;  // 32 x 8
#pragma unroll
  for (int i = 0; i < 32; i += 8)
    tile[ty + i][tx] = in[(size_t)(by + ty + i) * C + (bx + tx)];
  __syncthreads();
#pragma unroll
  for (int i = 0; i < 32; i += 8)
    out[(size_t)(bx + ty + i) * R + (by + tx)] = bf16_rn(tile[tx][ty + i]);
}

__global__ void init_state(const float* __restrict__ y0, float* __restrict__ y32,
                           float* __restrict__ z32, u16* __restrict__ zbf, int n) {
  const int i = blockIdx.x * blockDim.x + threadIdx.x;
  if (i < n) {
    const float v = y0[i];
    y32[i] = v;
    z32[i] = v;
    zbf[i] = bf16_rn(v);
  }
}

extern "C" void kernel_launch(void* const* d_in, const int* in_sizes, int n_in,
                              void* d_out, int out_size, void* d_ws, size_t ws_size,
                              hipStream_t stream) {
  const float* y0 = (const float*)d_in[0];
  const float* W1 = (const float*)d_in[1];  // [512, 2048]
  const float* b1 = (const float*)d_in[2];  // [2048]
  const float* wt = (const float*)d_in[3];  // [2048]
  const float* W2 = (const float*)d_in[4];  // [2048, 512]
  const float* b2 = (const float*)d_in[5];  // [512]

  constexpr int B = 4096, D = 512, HID = 2048, NSTEP = 64;
  constexpr float Hh = 1.0f / 64.0f;

  char* ws = (char*)d_ws;
  u16* W1t = (u16*)ws; ws += (size_t)HID * D * 2;   // [2048][512] bf16
  u16* W2t = (u16*)ws; ws += (size_t)D * HID * 2;   // [512][2048] bf16
  u16* hid = (u16*)ws; ws += (size_t)B * HID * 2;   // [4096][2048] bf16
  float* z32 = (float*)ws; ws += (size_t)B * D * 4; // [4096][512] f32
  u16* ybf = (u16*)ws; ws += (size_t)B * D * 2;
  u16* zbf = (u16*)ws; ws += (size_t)B * D * 2;
  float* y32 = (float*)d_out;

  transpose_bf16<<<dim3(HID / 32, D / 32), dim3(32, 8), 0, stream>>>(W1, W1t, D, HID);
  transpose_bf16<<<dim3(D / 32, HID / 32), dim3(32, 8), 0, stream>>>(W2, W2t, HID, D);
  init_state<<<(B * D + 255) / 256, 256, 0, stream>>>(y0, y32, z32, zbf, B * D);

  for (int s = 0; s < NSTEP; ++s) {
    const float t0 = (float)s * Hh;
    const float t1 = (float)(s + 1) * Hh;
    // hidden = tanh(z @ W1 + b1 + t0*wt)   grid = 8*8*16 = 1024 (~3 blocks/CU)
    gemm_fused<64, 128, 128, 512, 0, 16><<<1024, 256, 0, stream>>>(
        zbf, W1t, b1, wt, t0, nullptr, nullptr, nullptr, hid, HID);
    // y = 0.999*y + 0.001*z + h*(hidden @ W2 + b2)   grid = 8*16*8 = 1024
    gemm_fused<32, 64, 256, 2048, 1, 8><<<1024, 256, 0, stream>>>(
        hid, W2t, b2, nullptr, 0.f, y32, z32, y32, ybf, D);
    // hidden = tanh(y @ W1 + b1 + t1*wt)
    gemm_fused<64, 128, 128, 512, 0, 16><<<1024, 256, 0, stream>>>(
        ybf, W1t, b1, wt, t1, nullptr, nullptr, nullptr, hid, HID);
    // z = z + h*(hidden @ W2 + b2)
    gemm_fused<32, 64, 256, 2048, 2, 8><<<1024, 256, 0, stream>>>(
        hid, W2t, b2, nullptr, 0.f, nullptr, z32, z32, zbf, D);
  }
}

// Round 10
// 4548.214 us; speedup vs baseline: 1.1372x; 1.1372x over previous
//
#include <hip/hip_runtime.h>
#include <hip/hip_bf16.h>

typedef __bf16 bf16x8 __attribute__((ext_vector_type(8)));
typedef float f32x4 __attribute__((ext_vector_type(4)));
typedef unsigned short u16;

#define GLD_LDS16(gp, lp) __builtin_amdgcn_global_load_lds( \
    (const __attribute__((address_space(1))) unsigned int*)(gp), \
    (__attribute__((address_space(3))) unsigned int*)(lp), 16, 0, 0)

__device__ __forceinline__ float tanh_fast(float x) {
  float e = __expf(2.0f * x);
  return 1.0f - __fdividef(2.0f, e + 1.0f);
}

__device__ __forceinline__ u16 bf16_rn(float x) {
  union { float f; unsigned u; } v; v.f = x;
  unsigned r = v.u + 0x7fffu + ((v.u >> 16) & 1u);
  return (u16)(r >> 16);
}

// ---------------------------------------------------------------------------
// GEMM-A (hidden): R8-proven kernel, unchanged. C = A x Bt^T, 128x128 tile,
// BK=128, 4 waves 2x2, T2 both-sides XOR swizzle, XCD m-band swizzle,
// direct fragment epilogue with fused bias + t*wt + tanh -> bf16.
// ---------------------------------------------------------------------------
template <int BM, int BN, int BK, int K, int NTL>
__global__ __launch_bounds__(256)
void gemm_hidden(const u16* __restrict__ A, const u16* __restrict__ Bt,
                 const float* __restrict__ bias, const float* __restrict__ wt,
                 float tval, u16* __restrict__ out_bf, int N) {
  constexpr int NS = BK / 64;
  constexpr int WTM = BM / 2, WTN = BN / 2;
  constexpr int FM = WTM / 16, FN = WTN / 16;
  constexpr int ACH = BM * BK * 2 / 1024;
  constexpr int BCH = BN * BK * 2 / 1024;
  constexpr int CPS_A = BM / 8;
  constexpr int CPS_B = BN / 8;
  constexpr int MT = 4096 / BM;
  constexpr int MPX = MT / 8;

  __shared__ u16 As[NS * BM * 64];
  __shared__ u16 Bs[NS * BN * 64];

  const int tid = threadIdx.x;
  const int wave = tid >> 6;
  const int lane = tid & 63;
  const int wm = wave >> 1, wn = wave & 1;
  const int l15 = lane & 15, kg = lane >> 4;

  const int wg = blockIdx.x;
  const int xcd = wg & 7;
  const int j = wg >> 3;
  const int bm0 = (xcd * MPX + j / NTL) * BM;
  const int bn0 = (j % NTL) * BN;

  f32x4 acc[FM][FN];
#pragma unroll
  for (int m = 0; m < FM; ++m)
#pragma unroll
    for (int n = 0; n < FN; ++n) acc[m][n] = (f32x4){0.f, 0.f, 0.f, 0.f};

  const int sr = lane >> 3;
  const int scs = ((lane & 7) ^ sr) * 8;
  const int rsw = (l15 & 7) << 3;

  const u16* Ag = A + (size_t)bm0 * K;
  const u16* Bg = Bt + (size_t)bn0 * K;

  for (int kt = 0; kt < K / BK; ++kt) {
    const u16* Ak = Ag + kt * BK;
    const u16* Bk = Bg + kt * BK;
#pragma unroll
    for (int i = 0; i < ACH / 4; ++i) {
      const int ch = wave + i * 4;
      const int kh = ch / CPS_A;
      const int rg = ch % CPS_A;
      GLD_LDS16(Ak + (size_t)(rg * 8 + sr) * K + kh * 64 + scs,
                (char*)As + ch * 1024);
    }
#pragma unroll
    for (int i = 0; i < BCH / 4; ++i) {
      const int ch = wave + i * 4;
      const int kh = ch / CPS_B;
      const int rg = ch % CPS_B;
      GLD_LDS16(Bk + (size_t)(rg * 8 + sr) * K + kh * 64 + scs,
                (char*)Bs + ch * 1024);
    }
    __syncthreads();
#pragma unroll
    for (int ks = 0; ks < 2 * NS; ++ks) {
      const int kh = ks >> 1;
      const int kc = ((ks & 1) * 32 + kg * 8) ^ rsw;
      bf16x8 af[FM], bfr[FN];
#pragma unroll
      for (int m = 0; m < FM; ++m)
        af[m] = *reinterpret_cast<const bf16x8*>(
            &As[(kh * BM + wm * WTM + m * 16 + l15) * 64 + kc]);
#pragma unroll
      for (int n = 0; n < FN; ++n)
        bfr[n] = *reinterpret_cast<const bf16x8*>(
            &Bs[(kh * BN + wn * WTN + n * 16 + l15) * 64 + kc]);
#pragma unroll
      for (int m = 0; m < FM; ++m)
#pragma unroll
        for (int n = 0; n < FN; ++n)
          acc[m][n] =
              __builtin_amdgcn_mfma_f32_16x16x32_bf16(af[m], bfr[n], acc[m][n], 0, 0, 0);
    }
    __syncthreads();
  }

#pragma unroll
  for (int n = 0; n < FN; ++n) {
    const int col = bn0 + wn * WTN + n * 16 + l15;
    const float bv = bias[col] + tval * wt[col];
#pragma unroll
    for (int m = 0; m < FM; ++m) {
      const int row0 = bm0 + wm * WTM + m * 16 + kg * 4;
#pragma unroll
      for (int r = 0; r < 4; ++r)
        out_bf[(size_t)(row0 + r) * N + col] = bf16_rn(tanh_fast(acc[m][n][r] + bv));
    }
  }
}

// ---------------------------------------------------------------------------
// GEMM-B (state update), R10: wave-level K-split-4.
// 64x64 tile, BK=256, grid 512 (2 blocks/CU). Each of the 4 waves computes the
// FULL 64x64 output for its K-quarter (ks = 2*wave + {0,1} of 8 per K-tile):
// per-wave frags 4x4 -> block LDS reads per iter halve vs R8 (64 vs 128) at
// identical MFMA count -> LDS ratio 2.47x -> 1.24x. Partials reduced through
// the dead 64KB staging LDS in fixed w0+w1+w2+w3 order (deterministic), fused
// with the y/z update using coalesced f32x4 / ushort4 I/O.
// MODE 1: v = 0.999*y + 0.001*z + h*(acc+bias); out32 = v; out_bf = v
// MODE 2: v = z + h*(acc+bias);                 out32 = v; out_bf = v
// ---------------------------------------------------------------------------
template <int MODE>
__global__ __launch_bounds__(256)
void gemm_update(const u16* __restrict__ A, const u16* __restrict__ Bt,
                 const float* __restrict__ bias,
                 const float* __restrict__ y_in, const float* __restrict__ z_in,
                 float* __restrict__ out32, u16* __restrict__ out_bf) {
  constexpr int BM = 64, BN = 64, BK = 256, K = 2048, N = 512, NTL = 8;
  constexpr int NS = BK / 64;              // 4 slabs
  constexpr int NT = K / BK;               // 8 K-tiles
  constexpr int CPS = BM / 8;              // 8 chunks per slab
  constexpr int MPX = (4096 / BM) / 8;     // 8 m-tiles per XCD

  __shared__ __align__(16) char smem[64 * 1024];
  u16* As = (u16*)smem;                    // 32KB: [slab][row][64]
  u16* Bs = (u16*)(smem + 32 * 1024);      // 32KB
  float* red = (float*)smem;               // 64KB reduction reuse

  const int tid = threadIdx.x;
  const int wave = tid >> 6;
  const int lane = tid & 63;
  const int l15 = lane & 15, kg = lane >> 4;

  const int wg = blockIdx.x;
  const int xcd = wg & 7;
  const int j = wg >> 3;
  const int bm0 = (xcd * MPX + j / NTL) * BM;
  const int bn0 = (j % NTL) * BN;

  f32x4 acc[4][4];
#pragma unroll
  for (int m = 0; m < 4; ++m)
#pragma unroll
    for (int n = 0; n < 4; ++n) acc[m][n] = (f32x4){0.f, 0.f, 0.f, 0.f};

  const int sr = lane >> 3;
  const int scs = ((lane & 7) ^ sr) * 8;   // pre-swizzled src col
  const int rsw = (l15 & 7) << 3;          // read-side XOR

  const u16* Ag = A + (size_t)bm0 * K;
  const u16* Bg = Bt + (size_t)bn0 * K;

  for (int kt = 0; kt < NT; ++kt) {
    const u16* Ak = Ag + kt * BK;
    const u16* Bk = Bg + kt * BK;
#pragma unroll
    for (int i = 0; i < 8; ++i) {
      const int ch = wave + i * 4;
      const int kh = ch / CPS;
      const int rg = ch % CPS;
      GLD_LDS16(Ak + (size_t)(rg * 8 + sr) * K + kh * 64 + scs,
                (char*)As + ch * 1024);
    }
#pragma unroll
    for (int i = 0; i < 8; ++i) {
      const int ch = wave + i * 4;
      const int kh = ch / CPS;
      const int rg = ch % CPS;
      GLD_LDS16(Bk + (size_t)(rg * 8 + sr) * K + kh * 64 + scs,
                (char*)Bs + ch * 1024);
    }
    __syncthreads();
    // this wave's K-quarter: 2 of the 8 ks slices
#pragma unroll
    for (int ks2 = 0; ks2 < 2; ++ks2) {
      const int ks = wave * 2 + ks2;
      const int kh = ks >> 1;
      const int kc = ((ks & 1) * 32 + kg * 8) ^ rsw;
      bf16x8 af[4], bfr[4];
#pragma unroll
      for (int m = 0; m < 4; ++m)
        af[m] = *reinterpret_cast<const bf16x8*>(
            &As[(kh * BM + m * 16 + l15) * 64 + kc]);
#pragma unroll
      for (int n = 0; n < 4; ++n)
        bfr[n] = *reinterpret_cast<const bf16x8*>(
            &Bs[(kh * BN + n * 16 + l15) * 64 + kc]);
#pragma unroll
      for (int m = 0; m < 4; ++m)
#pragma unroll
        for (int n = 0; n < 4; ++n)
          acc[m][n] =
              __builtin_amdgcn_mfma_f32_16x16x32_bf16(af[m], bfr[n], acc[m][n], 0, 0, 0);
    }
    __syncthreads();  // waves done reading before next stage / reduction reuse
  }

  // Stage partials: wave w -> red[w*4096 + row*64 + col]
  {
    float* my = red + wave * 4096;
#pragma unroll
    for (int m = 0; m < 4; ++m)
#pragma unroll
      for (int n = 0; n < 4; ++n)
#pragma unroll
        for (int r = 0; r < 4; ++r)
          my[(m * 16 + kg * 4 + r) * 64 + n * 16 + l15] = acc[m][n][r];
  }
  __syncthreads();

  // Reduce 4 partials + fused update, coalesced 16B I/O.
  const int row = tid >> 2;
  const int cq = (tid & 3) * 16;
  const size_t gbase = (size_t)(bm0 + row) * N + bn0 + cq;
#pragma unroll
  for (int i = 0; i < 4; ++i) {
    const int lidx = row * 64 + cq + i * 4;
    const f32x4 p0 = *reinterpret_cast<const f32x4*>(&red[lidx]);
    const f32x4 p1 = *reinterpret_cast<const f32x4*>(&red[4096 + lidx]);
    const f32x4 p2 = *reinterpret_cast<const f32x4*>(&red[8192 + lidx]);
    const f32x4 p3 = *reinterpret_cast<const f32x4*>(&red[12288 + lidx]);
    const f32x4 bv = *reinterpret_cast<const f32x4*>(&bias[bn0 + cq + i * 4]);
    const f32x4 z4 = *reinterpret_cast<const f32x4*>(&z_in[gbase + i * 4]);
    f32x4 v;
    if (MODE == 1) {
      const f32x4 y4 = *reinterpret_cast<const f32x4*>(&y_in[gbase + i * 4]);
#pragma unroll
      for (int q = 0; q < 4; ++q) {
        const float s = ((p0[q] + p1[q]) + (p2[q] + p3[q])) + bv[q];
        v[q] = 0.999f * y4[q] + 0.001f * z4[q] + 0.015625f * s;
      }
    } else {
#pragma unroll
      for (int q = 0; q < 4; ++q) {
        const float s = ((p0[q] + p1[q]) + (p2[q] + p3[q])) + bv[q];
        v[q] = z4[q] + 0.015625f * s;
      }
    }
    *reinterpret_cast<f32x4*>(&out32[gbase + i * 4]) = v;
    ushort4 pb;
    pb.x = bf16_rn(v[0]); pb.y = bf16_rn(v[1]);
    pb.z = bf16_rn(v[2]); pb.w = bf16_rn(v[3]);
    *reinterpret_cast<ushort4*>(&out_bf[gbase + i * 4]) = pb;
  }
}

// in: [R, C] f32  ->  out: [C, R] bf16
__global__ void transpose_bf16(const float* __restrict__ in, u16* __restrict__ out,
                               int R, int C) {
  __shared__ float tile[32][33];
  const int bx = blockIdx.x * 32;
  const int by = blockIdx.y * 32;
  const int tx = threadIdx.x, ty = threadIdx.y;  // 32 x 8
#pragma unroll
  for (int i = 0; i < 32; i += 8)
    tile[ty + i][tx] = in[(size_t)(by + ty + i) * C + (bx + tx)];
  __syncthreads();
#pragma unroll
  for (int i = 0; i < 32; i += 8)
    out[(size_t)(bx + ty + i) * R + (by + tx)] = bf16_rn(tile[tx][ty + i]);
}

__global__ void init_state(const float* __restrict__ y0, float* __restrict__ y32,
                           float* __restrict__ z32, u16* __restrict__ zbf, int n) {
  const int i = blockIdx.x * blockDim.x + threadIdx.x;
  if (i < n) {
    const float v = y0[i];
    y32[i] = v;
    z32[i] = v;
    zbf[i] = bf16_rn(v);
  }
}

extern "C" void kernel_launch(void* const* d_in, const int* in_sizes, int n_in,
                              void* d_out, int out_size, void* d_ws, size_t ws_size,
                              hipStream_t stream) {
  const float* y0 = (const float*)d_in[0];
  const float* W1 = (const float*)d_in[1];  // [512, 2048]
  const float* b1 = (const float*)d_in[2];  // [2048]
  const float* wt = (const float*)d_in[3];  // [2048]
  const float* W2 = (const float*)d_in[4];  // [2048, 512]
  const float* b2 = (const float*)d_in[5];  // [512]

  constexpr int B = 4096, D = 512, HID = 2048, NSTEP = 64;
  constexpr float Hh = 1.0f / 64.0f;

  char* ws = (char*)d_ws;
  u16* W1t = (u16*)ws; ws += (size_t)HID * D * 2;   // [2048][512] bf16
  u16* W2t = (u16*)ws; ws += (size_t)D * HID * 2;   // [512][2048] bf16
  u16* hid = (u16*)ws; ws += (size_t)B * HID * 2;   // [4096][2048] bf16
  float* z32 = (float*)ws; ws += (size_t)B * D * 4; // [4096][512] f32
  u16* ybf = (u16*)ws; ws += (size_t)B * D * 2;
  u16* zbf = (u16*)ws; ws += (size_t)B * D * 2;
  float* y32 = (float*)d_out;

  transpose_bf16<<<dim3(HID / 32, D / 32), dim3(32, 8), 0, stream>>>(W1, W1t, D, HID);
  transpose_bf16<<<dim3(D / 32, HID / 32), dim3(32, 8), 0, stream>>>(W2, W2t, HID, D);
  init_state<<<(B * D + 255) / 256, 256, 0, stream>>>(y0, y32, z32, zbf, B * D);

  for (int s = 0; s < NSTEP; ++s) {
    const float t0 = (float)s * Hh;
    const float t1 = (float)(s + 1) * Hh;
    // hidden = tanh(z @ W1 + b1 + t0*wt)   512 blocks (32 m-tiles x 16 n-tiles)
    gemm_hidden<128, 128, 128, 512, 16><<<512, 256, 0, stream>>>(
        zbf, W1t, b1, wt, t0, hid, HID);
    // y = 0.999*y + 0.001*z + h*(hidden @ W2 + b2)   512 blocks
    gemm_update<1><<<512, 256, 0, stream>>>(hid, W2t, b2, y32, z32, y32, ybf);
    // hidden = tanh(y @ W1 + b1 + t1*wt)
    gemm_hidden<128, 128, 128, 512, 16><<<512, 256, 0, stream>>>(
        ybf, W1t, b1, wt, t1, hid, HID);
    // z = z + h*(hidden @ W2 + b2)
    gemm_update<2><<<512, 256, 0, stream>>>(hid, W2t, b2, nullptr, z32, z32, zbf);
  }
}